// Round 8
// baseline (158.495 us; speedup 1.0000x reference)
//
#include <hip/hip_runtime.h>

#define NPTS 8192
#define BN   16384          // B * N
#define D    32
#define R2   0.0009f        // float32(0.03**2)
#define SIMT 0.7f
#define RAD  0.03f
#define BLOCK 256
#define ZBINS 512
#define ZSCALE 1280.0f      // ZBINS / 0.4 (points lie in [0, 0.4))
#define AFIELDS 34          // nbc, cnt, acc[32]

// ---------------------------------------------------------------------------
// histscan: z-histograms + inv-norms + leafcnt; LAST block (ticket) runs the
// 4 prefix-scans wave-parallel with shuffles. Cross-block visibility via
// agent-scope atomics (hist written by atomicAdd; read by atomic loads).
// ---------------------------------------------------------------------------
__global__ __launch_bounds__(BLOCK) void histscan_kernel(
    const float* __restrict__ pts, const float* __restrict__ emb,
    const int* __restrict__ leaf, float* __restrict__ invn,
    int* __restrict__ histA, int* __restrict__ histL,
    int* __restrict__ leafcnt, unsigned* __restrict__ done,
    int* __restrict__ rsA, int* __restrict__ rsL,
    int* __restrict__ curA, int* __restrict__ curL) {
  const int p = blockIdx.x * BLOCK + threadIdx.x;
  const float z = pts[3 * p + 2];
  int bin = (int)(z * ZSCALE); if (bin > ZBINS - 1) bin = ZBINS - 1;
  const int b = p >> 13;
  const int lf = leaf[p] > 0;
  atomicAdd(&histA[b * ZBINS + bin], 1);
  if (lf) atomicAdd(&histL[b * ZBINS + bin], 1);

  const float4* er = (const float4*)(emb + (size_t)p * D);
  float ss = 0.f;
#pragma unroll
  for (int i = 0; i < D / 4; ++i) {
    float4 v = er[i];
    ss += v.x * v.x + v.y * v.y + v.z * v.z + v.w * v.w;
  }
  invn[p] = 1.0f / fmaxf(sqrtf(ss), 1e-8f);

  const unsigned long long m = __ballot(lf);
  if ((threadIdx.x & 63) == 0) atomicAdd(&leafcnt[b], (int)__popcll(m));

  // ---- ticket: last finished block does the scans ----
  __shared__ int islast;
  __threadfence();
  if (threadIdx.x == 0) {
    const unsigned t = __hip_atomic_fetch_add(done, 1u, __ATOMIC_ACQ_REL,
                                              __HIP_MEMORY_SCOPE_AGENT);
    islast = (t == gridDim.x - 1);
  }
  __syncthreads();
  if (!islast) return;

  const int wv = threadIdx.x >> 6;      // wave 0..3: {A:b0, A:b1, L:b0, L:b1}
  const int lane = threadIdx.x & 63;
  const int sb = wv & 1;
  const int* __restrict__ h = (wv < 2) ? histA : histL;
  int* __restrict__ rs = (wv < 2) ? rsA : rsL;
  int* __restrict__ cu = (wv < 2) ? curA : curL;
  int carry = 0;
  for (int c = 0; c < ZBINS / 64; ++c) {
    const int idx = c * 64 + lane;
    const int v = __hip_atomic_load(&h[sb * ZBINS + idx], __ATOMIC_RELAXED,
                                    __HIP_MEMORY_SCOPE_AGENT);
    int incl = v;
#pragma unroll
    for (int off = 1; off < 64; off <<= 1) {
      const int t = __shfl_up(incl, off);
      if (lane >= off) incl += t;
    }
    const int excl = carry + incl - v;
    rs[sb * (ZBINS + 1) + idx] = excl;
    cu[sb * ZBINS + idx] = excl;
    carry += __shfl(incl, 63);
  }
  if (lane == 0) rs[sb * (ZBINS + 1) + ZBINS] = carry;
}

// ---------------------------------------------------------------------------
// scatter: counting-sort by z-bin. All points -> sortedA (+perm); leaf points
// -> compacted j-side arrays (pts4L with folded 0.5*(sq-R2), invL, embL).
// ---------------------------------------------------------------------------
__global__ __launch_bounds__(BLOCK) void scatter_kernel(
    const float* __restrict__ pts, const float* __restrict__ emb,
    const int* __restrict__ leaf, const float* __restrict__ invn,
    int* __restrict__ curA, int* __restrict__ curL,
    float4* __restrict__ sortedA, int* __restrict__ permA,
    float4* __restrict__ pts4L, float* __restrict__ invL,
    float* __restrict__ embL) {
  const int p = blockIdx.x * BLOCK + threadIdx.x;
  const float x = pts[3 * p + 0];
  const float y = pts[3 * p + 1];
  const float z = pts[3 * p + 2];
  const float sq = x * x + y * y + z * z;
  const int lf = leaf[p] > 0;
  const float inv = invn[p];
  int bin = (int)(z * ZSCALE); if (bin > ZBINS - 1) bin = ZBINS - 1;
  const int b = p >> 13;

  const int dst = b * NPTS + atomicAdd(&curA[b * ZBINS + bin], 1);
  sortedA[dst] = make_float4(x, y, z, lf ? inv : -inv);  // leaf in sign bit
  permA[dst] = p;

  if (lf) {
    const int dl = b * NPTS + atomicAdd(&curL[b * ZBINS + bin], 1);
    pts4L[dl] = make_float4(x, y, z, 0.5f * (sq - R2));
    invL[dl] = inv;
    const float4* __restrict__ s4 = (const float4*)(emb + (size_t)p * D);
    float4* __restrict__ d4 = (float4*)(embL + (size_t)dl * D);
#pragma unroll
    for (int k = 0; k < D / 4; ++k) d4[k] = s4[k];
  }
}

// ---------------------------------------------------------------------------
// pair + fused reduce/MLP: 1 block per 64 sorted i's; the block's 4 waves
// split the ig's whole leaf-window 4 ways (bounds readfirstlane-uniform ->
// scalar j loads, 8-wide double-buffered). Waves combine in LDS, then wave 0
// runs the MLP epilogue for the 64 points and scatters out via perm.
// No global partials, no separate reduce dispatch.
// ---------------------------------------------------------------------------
__global__ __launch_bounds__(BLOCK) void pair_kernel(
    const float4* __restrict__ sortedA, const int* __restrict__ permA,
    const float4* __restrict__ pts4L, const float* __restrict__ invL,
    const float* __restrict__ embL, const float* __restrict__ emb,
    const int* __restrict__ rsL, const int* __restrict__ leafcnt,
    const float* __restrict__ W1, const float* __restrict__ b1,
    const float* __restrict__ W2, const float* __restrict__ b2,
    float* __restrict__ out) {
  const int ig   = blockIdx.x;            // i-group of 64 (0..255)
  const int b    = ig >> 7;               // 128 i-groups per batch
  const int lane = threadIdx.x & 63;
  const int wv   = threadIdx.x >> 6;      // wave 0..3
  const int sg   = ig * 64 + lane;

  __shared__ float red[AFIELDS][64];
  for (int t = threadIdx.x; t < AFIELDS * 64; t += BLOCK)
    (&red[0][0])[t] = 0.f;
  __syncthreads();

  const float4 A = sortedA[sg];
  const float inv_i = fabsf(A.w);
  const float mhsq = -0.5f * (A.x * A.x + A.y * A.y + A.z * A.z);
  const int p = permA[sg];

  float4 ei[D / 4];                       // e_i; reused as passthrough in tail
  {
    const float4* __restrict__ e4 = (const float4*)(emb + (size_t)p * D);
#pragma unroll
    for (int k = 0; k < D / 4; ++k) ei[k] = e4[k];
  }

  float zmin = A.z, zmax = A.z;
#pragma unroll
  for (int off = 1; off < 64; off <<= 1) {
    zmin = fminf(zmin, __shfl_xor(zmin, off));
    zmax = fmaxf(zmax, __shfl_xor(zmax, off));
  }
  int klo = (int)((zmin - RAD) * ZSCALE) - 1; if (klo < 0) klo = 0;  // fp slack
  int khi = (int)((zmax + RAD) * ZSCALE) + 1; if (khi > ZBINS - 1) khi = ZBINS - 1;
  klo = __builtin_amdgcn_readfirstlane(klo);
  khi = __builtin_amdgcn_readfirstlane(khi);
  const int jlo = b * NPTS + rsL[b * (ZBINS + 1) + klo];
  const int jhi = b * NPTS + rsL[b * (ZBINS + 1) + khi + 1];
  const int len = jhi - jlo;
  int c0 = jlo + (len * wv) / 4;
  int c1 = jlo + (len * (wv + 1)) / 4;
  c0 = __builtin_amdgcn_readfirstlane(c0);
  c1 = __builtin_amdgcn_readfirstlane(c1);

  float acc[D];
#pragma unroll
  for (int d = 0; d < D; ++d) acc[d] = 0.f;
  float nbc = 0.f, cnt = 0.f;

  auto process = [&](const float4 c, const int jj) {
    const float t = fmaf(A.z, c.z, fmaf(A.y, c.y, fmaf(A.x, c.x, mhsq)));
    if (t > c.w) {                        // d2 < R2; j is leaf by construction
      nbc += 1.0f;
      const float4* __restrict__ ej4 = (const float4*)(embL + (size_t)jj * D);
      float s0 = 0.f, s1 = 0.f, s2 = 0.f, s3 = 0.f;
#pragma unroll
      for (int k = 0; k < D / 4; ++k) {
        const float4 vj = ej4[k];         // uniform jj -> scalar loads
        s0 = fmaf(ei[k].x, vj.x, s0);
        s1 = fmaf(ei[k].y, vj.y, s1);
        s2 = fmaf(ei[k].z, vj.z, s2);
        s3 = fmaf(ei[k].w, vj.w, s3);
      }
      const float s = ((s0 + s1) + (s2 + s3)) * inv_i * invL[jj];
      if (s > SIMT) {
        cnt += 1.0f;
#pragma unroll
        for (int k = 0; k < D / 4; ++k) {
          const float4 vj = ej4[k];
          acc[4 * k + 0] += vj.x;
          acc[4 * k + 1] += vj.y;
          acc[4 * k + 2] += vj.z;
          acc[4 * k + 3] += vj.w;
        }
      }
    }
  };

  const int nfull = (c1 - c0) & ~7;
  if (nfull > 0) {
    float4 cur[8], nxt[8];
#pragma unroll
    for (int u = 0; u < 8; ++u) cur[u] = pts4L[c0 + u];
    for (int j = c0; j < c0 + nfull; j += 8) {
      const int jn = (j + 8 < c0 + nfull) ? (j + 8) : c0;  // wrap: in-bounds
#pragma unroll
      for (int u = 0; u < 8; ++u) nxt[u] = pts4L[jn + u];
#pragma unroll
      for (int u = 0; u < 8; ++u) process(cur[u], j + u);
#pragma unroll
      for (int u = 0; u < 8; ++u) cur[u] = nxt[u];
    }
  }
  for (int j = c0 + nfull; j < c1; ++j) process(pts4L[j], j);

  // combine the block's 4 waves in LDS (sparse ds-atomics)
  if (nbc != 0.f) atomicAdd(&red[0][lane], nbc);
  if (cnt != 0.f) {
    atomicAdd(&red[1][lane], cnt);
#pragma unroll
    for (int d = 0; d < D; ++d) atomicAdd(&red[2 + d][lane], acc[d]);
  }
  __syncthreads();

  // ---- fused epilogue: wave 0, one lane per point ----
  if (threadIdx.x < 64) {
    const float tnbc = red[0][lane];
    const float tcnt = red[1][lane];
    const float rinv = 1.0f / fmaxf(tcnt, 1.0f);

    float e[D];
#pragma unroll
    for (int k = 0; k < D / 4; ++k) {
      e[4 * k + 0] = ei[k].x; e[4 * k + 1] = ei[k].y;
      e[4 * k + 2] = ei[k].z; e[4 * k + 3] = ei[k].w;
    }

    float h[D];
#pragma unroll
    for (int k = 0; k < D; ++k) h[k] = b1[k];
    for (int d = 0; d < D; ++d) {
      const float c = e[d];
      const float* __restrict__ w = W1 + (size_t)d * D;
#pragma unroll
      for (int k = 0; k < D; ++k) h[k] = fmaf(c, w[k], h[k]);
    }
    for (int d = 0; d < D; ++d) {
      const float c = red[2 + d][lane] * rinv;   // mean_sim[d]
      const float* __restrict__ w = W1 + (size_t)(D + d) * D;
#pragma unroll
      for (int k = 0; k < D; ++k) h[k] = fmaf(c, w[k], h[k]);
    }
#pragma unroll
    for (int k = 0; k < D; ++k) h[k] = fmaxf(h[k], 0.f);

    float o[D];
#pragma unroll
    for (int m = 0; m < D; ++m) o[m] = b2[m];
    for (int k = 0; k < D; ++k) {
      const float c = h[k];
      const float* __restrict__ w = W2 + (size_t)k * D;
#pragma unroll
      for (int m = 0; m < D; ++m) o[m] = fmaf(c, w[m], o[m]);
    }

    const bool lf = A.w > 0.f;
    const bool cond = lf && (tnbc >= 2.0f) && (tcnt >= 1.0f) && (leafcnt[b] >= 10);

    float4* outr = (float4*)(out + (size_t)p * D);
#pragma unroll
    for (int i = 0; i < D / 4; ++i) {
      float4 v;
      if (cond) { v.x = o[4*i+0]; v.y = o[4*i+1]; v.z = o[4*i+2]; v.w = o[4*i+3]; }
      else      { v = ei[i]; }
      outr[i] = v;
    }
  }
}

// ---------------------------------------------------------------------------
extern "C" void kernel_launch(void* const* d_in, const int* in_sizes, int n_in,
                              void* d_out, int out_size, void* d_ws, size_t ws_size,
                              hipStream_t stream) {
  (void)in_sizes; (void)n_in; (void)out_size; (void)ws_size;
  const float* pts  = (const float*)d_in[0];
  const float* emb  = (const float*)d_in[1];
  const int*   leaf = (const int*)d_in[2];
  const float* W1   = (const float*)d_in[3];
  const float* b1   = (const float*)d_in[4];
  const float* W2   = (const float*)d_in[5];
  const float* b2   = (const float*)d_in[6];
  float* out = (float*)d_out;

  char* ws = (char*)d_ws;
  size_t off = 0;
  auto alloc = [&](size_t bytes) { void* r = ws + off; off = (off + bytes + 15) & ~(size_t)15; return r; };

  float4*   sortedA = (float4*)alloc((size_t)BN * 16);
  int*      permA   = (int*)alloc((size_t)BN * 4);
  float4*   pts4L   = (float4*)alloc((size_t)BN * 16);
  float*    invL    = (float*)alloc((size_t)BN * 4);
  float*    embL    = (float*)alloc((size_t)BN * D * 4);
  float*    invn    = (float*)alloc((size_t)BN * 4);
  int*      rsA     = (int*)alloc(2 * (ZBINS + 1) * 4);
  int*      rsL     = (int*)alloc(2 * (ZBINS + 1) * 4);
  int*      curA    = (int*)alloc(2 * ZBINS * 4);
  int*      curL    = (int*)alloc(2 * ZBINS * 4);
  int*      histA   = (int*)alloc(2 * ZBINS * 4);   // histA..done contiguous
  int*      histL   = (int*)alloc(2 * ZBINS * 4);   //   -> single 8.2 KB memset
  int*      leafcnt = (int*)alloc(16);
  unsigned* done    = (unsigned*)alloc(16);

  hipMemsetAsync(histA, 0, 2 * (2 * ZBINS * 4) + 32, stream);
  histscan_kernel<<<BN / BLOCK, BLOCK, 0, stream>>>(
      pts, emb, leaf, invn, histA, histL, leafcnt, done, rsA, rsL, curA, curL);
  scatter_kernel<<<BN / BLOCK, BLOCK, 0, stream>>>(
      pts, emb, leaf, invn, curA, curL, sortedA, permA, pts4L, invL, embL);
  pair_kernel<<<BN / 64, BLOCK, 0, stream>>>(
      sortedA, permA, pts4L, invL, embL, emb, rsL, leafcnt,
      W1, b1, W2, b2, out);
}

// Round 9
// 123.601 us; speedup vs baseline: 1.2823x; 1.2823x over previous
//
#include <hip/hip_runtime.h>

#define NPTS 8192
#define BN   16384          // B * N
#define D    32
#define R2   0.0009f        // float32(0.03**2)
#define SIMT 0.7f
#define RAD  0.03f
#define BLOCK 256
#define PBLOCK 1024         // pair kernel: 16 waves/block -> 4 waves/SIMD
#define PWAVES 16
#define ZBINS 512
#define ZSCALE 1280.0f      // ZBINS / 0.4 (points lie in [0, 0.4))
#define AFIELDS 34          // nbc, cnt, acc[32]

// ---------------------------------------------------------------------------
// histscan: z-histograms + inv-norms + leafcnt; LAST block (ticket) runs the
// 4 prefix-scans wave-parallel with shuffles. Cross-block visibility via
// agent-scope atomics (hist written by atomicAdd; read by atomic loads).
// ---------------------------------------------------------------------------
__global__ __launch_bounds__(BLOCK) void histscan_kernel(
    const float* __restrict__ pts, const float* __restrict__ emb,
    const int* __restrict__ leaf, float* __restrict__ invn,
    int* __restrict__ histA, int* __restrict__ histL,
    int* __restrict__ leafcnt, unsigned* __restrict__ done,
    int* __restrict__ rsA, int* __restrict__ rsL,
    int* __restrict__ curA, int* __restrict__ curL) {
  const int p = blockIdx.x * BLOCK + threadIdx.x;
  const float z = pts[3 * p + 2];
  int bin = (int)(z * ZSCALE); if (bin > ZBINS - 1) bin = ZBINS - 1;
  const int b = p >> 13;
  const int lf = leaf[p] > 0;
  atomicAdd(&histA[b * ZBINS + bin], 1);
  if (lf) atomicAdd(&histL[b * ZBINS + bin], 1);

  const float4* er = (const float4*)(emb + (size_t)p * D);
  float ss = 0.f;
#pragma unroll
  for (int i = 0; i < D / 4; ++i) {
    float4 v = er[i];
    ss += v.x * v.x + v.y * v.y + v.z * v.z + v.w * v.w;
  }
  invn[p] = 1.0f / fmaxf(sqrtf(ss), 1e-8f);

  const unsigned long long m = __ballot(lf);
  if ((threadIdx.x & 63) == 0) atomicAdd(&leafcnt[b], (int)__popcll(m));

  // ---- ticket: last finished block does the scans ----
  __shared__ int islast;
  __threadfence();
  if (threadIdx.x == 0) {
    const unsigned t = __hip_atomic_fetch_add(done, 1u, __ATOMIC_ACQ_REL,
                                              __HIP_MEMORY_SCOPE_AGENT);
    islast = (t == gridDim.x - 1);
  }
  __syncthreads();
  if (!islast) return;

  const int wv = threadIdx.x >> 6;      // wave 0..3: {A:b0, A:b1, L:b0, L:b1}
  const int lane = threadIdx.x & 63;
  const int sb = wv & 1;
  const int* __restrict__ h = (wv < 2) ? histA : histL;
  int* __restrict__ rs = (wv < 2) ? rsA : rsL;
  int* __restrict__ cu = (wv < 2) ? curA : curL;
  int carry = 0;
  for (int c = 0; c < ZBINS / 64; ++c) {
    const int idx = c * 64 + lane;
    const int v = __hip_atomic_load(&h[sb * ZBINS + idx], __ATOMIC_RELAXED,
                                    __HIP_MEMORY_SCOPE_AGENT);
    int incl = v;
#pragma unroll
    for (int off = 1; off < 64; off <<= 1) {
      const int t = __shfl_up(incl, off);
      if (lane >= off) incl += t;
    }
    const int excl = carry + incl - v;
    rs[sb * (ZBINS + 1) + idx] = excl;
    cu[sb * ZBINS + idx] = excl;
    carry += __shfl(incl, 63);
  }
  if (lane == 0) rs[sb * (ZBINS + 1) + ZBINS] = carry;
}

// ---------------------------------------------------------------------------
// scatter: counting-sort by z-bin. All points -> sortedA (+perm); leaf points
// -> compacted j-side arrays (pts4L with folded 0.5*(sq-R2), invL, embL).
// ---------------------------------------------------------------------------
__global__ __launch_bounds__(BLOCK) void scatter_kernel(
    const float* __restrict__ pts, const float* __restrict__ emb,
    const int* __restrict__ leaf, const float* __restrict__ invn,
    int* __restrict__ curA, int* __restrict__ curL,
    float4* __restrict__ sortedA, int* __restrict__ permA,
    float4* __restrict__ pts4L, float* __restrict__ invL,
    float* __restrict__ embL) {
  const int p = blockIdx.x * BLOCK + threadIdx.x;
  const float x = pts[3 * p + 0];
  const float y = pts[3 * p + 1];
  const float z = pts[3 * p + 2];
  const float sq = x * x + y * y + z * z;
  const int lf = leaf[p] > 0;
  const float inv = invn[p];
  int bin = (int)(z * ZSCALE); if (bin > ZBINS - 1) bin = ZBINS - 1;
  const int b = p >> 13;

  const int dst = b * NPTS + atomicAdd(&curA[b * ZBINS + bin], 1);
  sortedA[dst] = make_float4(x, y, z, lf ? inv : -inv);  // leaf in sign bit
  permA[dst] = p;

  if (lf) {
    const int dl = b * NPTS + atomicAdd(&curL[b * ZBINS + bin], 1);
    pts4L[dl] = make_float4(x, y, z, 0.5f * (sq - R2));
    invL[dl] = inv;
    const float4* __restrict__ s4 = (const float4*)(emb + (size_t)p * D);
    float4* __restrict__ d4 = (float4*)(embL + (size_t)dl * D);
#pragma unroll
    for (int k = 0; k < D / 4; ++k) d4[k] = s4[k];
  }
}

// ---------------------------------------------------------------------------
// pair + fused reduce/MLP: 1 block (16 waves) per 64 sorted i's; the waves
// split the ig's leaf-window 16 ways (bounds readfirstlane-uniform -> scalar
// j loads, 8-wide double-buffered). R8 lesson: 4 waves/block = 1 wave/SIMD
// had nothing to hide s_load latency (VALUBusy 8%); 16 waves = 4/SIMD covers
// ~200cy s_load with ~256cy of issue. Waves combine in LDS; wave 0 runs the
// MLP epilogue and scatters out via perm.
// ---------------------------------------------------------------------------
__global__ __launch_bounds__(PBLOCK) void pair_kernel(
    const float4* __restrict__ sortedA, const int* __restrict__ permA,
    const float4* __restrict__ pts4L, const float* __restrict__ invL,
    const float* __restrict__ embL, const float* __restrict__ emb,
    const int* __restrict__ rsL, const int* __restrict__ leafcnt,
    const float* __restrict__ W1, const float* __restrict__ b1,
    const float* __restrict__ W2, const float* __restrict__ b2,
    float* __restrict__ out) {
  const int ig   = blockIdx.x;            // i-group of 64 (0..255)
  const int b    = ig >> 7;               // 128 i-groups per batch
  const int lane = threadIdx.x & 63;
  const int wv   = threadIdx.x >> 6;      // wave 0..15
  const int sg   = ig * 64 + lane;

  __shared__ float red[AFIELDS][64];
  for (int t = threadIdx.x; t < AFIELDS * 64; t += PBLOCK)
    (&red[0][0])[t] = 0.f;
  __syncthreads();

  const float4 A = sortedA[sg];
  const float inv_i = fabsf(A.w);
  const float mhsq = -0.5f * (A.x * A.x + A.y * A.y + A.z * A.z);
  const int p = permA[sg];

  float4 ei[D / 4];                       // e_i; reused as passthrough in tail
  {
    const float4* __restrict__ e4 = (const float4*)(emb + (size_t)p * D);
#pragma unroll
    for (int k = 0; k < D / 4; ++k) ei[k] = e4[k];
  }

  float zmin = A.z, zmax = A.z;
#pragma unroll
  for (int off = 1; off < 64; off <<= 1) {
    zmin = fminf(zmin, __shfl_xor(zmin, off));
    zmax = fmaxf(zmax, __shfl_xor(zmax, off));
  }
  int klo = (int)((zmin - RAD) * ZSCALE) - 1; if (klo < 0) klo = 0;  // fp slack
  int khi = (int)((zmax + RAD) * ZSCALE) + 1; if (khi > ZBINS - 1) khi = ZBINS - 1;
  klo = __builtin_amdgcn_readfirstlane(klo);
  khi = __builtin_amdgcn_readfirstlane(khi);
  const int jlo = b * NPTS + rsL[b * (ZBINS + 1) + klo];
  const int jhi = b * NPTS + rsL[b * (ZBINS + 1) + khi + 1];
  const int len = jhi - jlo;
  int c0 = jlo + (len * wv) / PWAVES;
  int c1 = jlo + (len * (wv + 1)) / PWAVES;
  c0 = __builtin_amdgcn_readfirstlane(c0);
  c1 = __builtin_amdgcn_readfirstlane(c1);

  float acc[D];
#pragma unroll
  for (int d = 0; d < D; ++d) acc[d] = 0.f;
  float nbc = 0.f, cnt = 0.f;

  auto process = [&](const float4 c, const int jj) {
    const float t = fmaf(A.z, c.z, fmaf(A.y, c.y, fmaf(A.x, c.x, mhsq)));
    if (t > c.w) {                        // d2 < R2; j is leaf by construction
      nbc += 1.0f;
      const float4* __restrict__ ej4 = (const float4*)(embL + (size_t)jj * D);
      float s0 = 0.f, s1 = 0.f, s2 = 0.f, s3 = 0.f;
#pragma unroll
      for (int k = 0; k < D / 4; ++k) {
        const float4 vj = ej4[k];         // uniform jj -> scalar loads
        s0 = fmaf(ei[k].x, vj.x, s0);
        s1 = fmaf(ei[k].y, vj.y, s1);
        s2 = fmaf(ei[k].z, vj.z, s2);
        s3 = fmaf(ei[k].w, vj.w, s3);
      }
      const float s = ((s0 + s1) + (s2 + s3)) * inv_i * invL[jj];
      if (s > SIMT) {
        cnt += 1.0f;
#pragma unroll
        for (int k = 0; k < D / 4; ++k) {
          const float4 vj = ej4[k];
          acc[4 * k + 0] += vj.x;
          acc[4 * k + 1] += vj.y;
          acc[4 * k + 2] += vj.z;
          acc[4 * k + 3] += vj.w;
        }
      }
    }
  };

  const int nfull = (c1 - c0) & ~7;
  if (nfull > 0) {
    float4 cur[8], nxt[8];
#pragma unroll
    for (int u = 0; u < 8; ++u) cur[u] = pts4L[c0 + u];
    for (int j = c0; j < c0 + nfull; j += 8) {
      const int jn = (j + 8 < c0 + nfull) ? (j + 8) : c0;  // wrap: in-bounds
#pragma unroll
      for (int u = 0; u < 8; ++u) nxt[u] = pts4L[jn + u];
#pragma unroll
      for (int u = 0; u < 8; ++u) process(cur[u], j + u);
#pragma unroll
      for (int u = 0; u < 8; ++u) cur[u] = nxt[u];
    }
  }
  for (int j = c0 + nfull; j < c1; ++j) process(pts4L[j], j);

  // combine the block's 16 waves in LDS (sparse ds-atomics)
  if (nbc != 0.f) atomicAdd(&red[0][lane], nbc);
  if (cnt != 0.f) {
    atomicAdd(&red[1][lane], cnt);
#pragma unroll
    for (int d = 0; d < D; ++d) atomicAdd(&red[2 + d][lane], acc[d]);
  }
  __syncthreads();

  // ---- fused epilogue: wave 0, one lane per point ----
  if (threadIdx.x < 64) {
    const float tnbc = red[0][lane];
    const float tcnt = red[1][lane];
    const float rinv = 1.0f / fmaxf(tcnt, 1.0f);

    float e[D];
#pragma unroll
    for (int k = 0; k < D / 4; ++k) {
      e[4 * k + 0] = ei[k].x; e[4 * k + 1] = ei[k].y;
      e[4 * k + 2] = ei[k].z; e[4 * k + 3] = ei[k].w;
    }

    float h[D];
#pragma unroll
    for (int k = 0; k < D; ++k) h[k] = b1[k];
    for (int d = 0; d < D; ++d) {
      const float c = e[d];
      const float* __restrict__ w = W1 + (size_t)d * D;
#pragma unroll
      for (int k = 0; k < D; ++k) h[k] = fmaf(c, w[k], h[k]);
    }
    for (int d = 0; d < D; ++d) {
      const float c = red[2 + d][lane] * rinv;   // mean_sim[d]
      const float* __restrict__ w = W1 + (size_t)(D + d) * D;
#pragma unroll
      for (int k = 0; k < D; ++k) h[k] = fmaf(c, w[k], h[k]);
    }
#pragma unroll
    for (int k = 0; k < D; ++k) h[k] = fmaxf(h[k], 0.f);

    float o[D];
#pragma unroll
    for (int m = 0; m < D; ++m) o[m] = b2[m];
    for (int k = 0; k < D; ++k) {
      const float c = h[k];
      const float* __restrict__ w = W2 + (size_t)k * D;
#pragma unroll
      for (int m = 0; m < D; ++m) o[m] = fmaf(c, w[m], o[m]);
    }

    const bool lf = A.w > 0.f;
    const bool cond = lf && (tnbc >= 2.0f) && (tcnt >= 1.0f) && (leafcnt[b] >= 10);

    float4* outr = (float4*)(out + (size_t)p * D);
#pragma unroll
    for (int i = 0; i < D / 4; ++i) {
      float4 v;
      if (cond) { v.x = o[4*i+0]; v.y = o[4*i+1]; v.z = o[4*i+2]; v.w = o[4*i+3]; }
      else      { v = ei[i]; }
      outr[i] = v;
    }
  }
}

// ---------------------------------------------------------------------------
extern "C" void kernel_launch(void* const* d_in, const int* in_sizes, int n_in,
                              void* d_out, int out_size, void* d_ws, size_t ws_size,
                              hipStream_t stream) {
  (void)in_sizes; (void)n_in; (void)out_size; (void)ws_size;
  const float* pts  = (const float*)d_in[0];
  const float* emb  = (const float*)d_in[1];
  const int*   leaf = (const int*)d_in[2];
  const float* W1   = (const float*)d_in[3];
  const float* b1   = (const float*)d_in[4];
  const float* W2   = (const float*)d_in[5];
  const float* b2   = (const float*)d_in[6];
  float* out = (float*)d_out;

  char* ws = (char*)d_ws;
  size_t off = 0;
  auto alloc = [&](size_t bytes) { void* r = ws + off; off = (off + bytes + 15) & ~(size_t)15; return r; };

  float4*   sortedA = (float4*)alloc((size_t)BN * 16);
  int*      permA   = (int*)alloc((size_t)BN * 4);
  float4*   pts4L   = (float4*)alloc((size_t)BN * 16);
  float*    invL    = (float*)alloc((size_t)BN * 4);
  float*    embL    = (float*)alloc((size_t)BN * D * 4);
  float*    invn    = (float*)alloc((size_t)BN * 4);
  int*      rsA     = (int*)alloc(2 * (ZBINS + 1) * 4);
  int*      rsL     = (int*)alloc(2 * (ZBINS + 1) * 4);
  int*      curA    = (int*)alloc(2 * ZBINS * 4);
  int*      curL    = (int*)alloc(2 * ZBINS * 4);
  int*      histA   = (int*)alloc(2 * ZBINS * 4);   // histA..done contiguous
  int*      histL   = (int*)alloc(2 * ZBINS * 4);   //   -> single 8.2 KB memset
  int*      leafcnt = (int*)alloc(16);
  unsigned* done    = (unsigned*)alloc(16);

  hipMemsetAsync(histA, 0, 2 * (2 * ZBINS * 4) + 32, stream);
  histscan_kernel<<<BN / BLOCK, BLOCK, 0, stream>>>(
      pts, emb, leaf, invn, histA, histL, leafcnt, done, rsA, rsL, curA, curL);
  scatter_kernel<<<BN / BLOCK, BLOCK, 0, stream>>>(
      pts, emb, leaf, invn, curA, curL, sortedA, permA, pts4L, invL, embL);
  pair_kernel<<<BN / 64, PBLOCK, 0, stream>>>(
      sortedA, permA, pts4L, invL, embL, emb, rsL, leafcnt,
      W1, b1, W2, b2, out);
}